// Round 3
// baseline (626.469 us; speedup 1.0000x reference)
//
#include <hip/hip_runtime.h>
#include <hip/hip_bf16.h>

// TupleAveragePredictor: out = sigmoid( relu( [mean(gnn_h[tuples[:,1:]]), gnn_h[triplets[:,2]]] @ W1^T + b1 ) @ W2^T + b2 )
// N_ROWS=200000, IN=256, K=2*IN=512, H=512.
// R3: FIX — swizzle XOR uses bits 4-6; bit 6 collides with the +=64 k-step
// increment, so incrementing the XORed address read wrong bytes and drifted
// past the row into idx_lds (int patterns = bf16 NaN). Now keep a LOGICAL
// offset and XOR at each use.

#define NROWS 200000
#define NNODES 100000
#define INF 256
#define KDIM 512
#define HF 512
#define BM 32

typedef __attribute__((ext_vector_type(8))) short short8;
typedef __attribute__((ext_vector_type(4))) float f32x4;

__device__ __align__(16) unsigned short g_W1b[HF * KDIM];  // 512 KB module-static

__device__ __forceinline__ unsigned short f2bf(float f) {
    unsigned int u = __float_as_uint(f);
    unsigned int r = (u + 0x7fffu + ((u >> 16) & 1u)) >> 16;
    return (unsigned short)r;
}

__global__ void convert_w1_kernel(const float* __restrict__ W1) {
    int i = (blockIdx.x * 256 + threadIdx.x) * 4;  // 262144 elems / 4 = 65536 thr
    float4 v = *(const float4*)(W1 + i);
    unsigned long long pk = (unsigned long long)f2bf(v.x)
        | ((unsigned long long)f2bf(v.y) << 16)
        | ((unsigned long long)f2bf(v.z) << 32)
        | ((unsigned long long)f2bf(v.w) << 48);
    *(unsigned long long*)(g_W1b + i) = pk;
}

__global__ __launch_bounds__(256)
void fused_kernel(const float* __restrict__ gnn_h,
                  const int* __restrict__ tuples,
                  const int* __restrict__ triplets,
                  const float* __restrict__ b1,
                  const float* __restrict__ W2,
                  const float* __restrict__ b2,
                  float* __restrict__ out) {
    __shared__ __align__(16) unsigned short x_lds[BM * KDIM];  // 32 KB, swizzled
    __shared__ int idx_lds[BM * 11];
    __shared__ int tgt_lds[BM];
    __shared__ float red[4][BM];

    const int t = threadIdx.x;
    const int g0 = blockIdx.x * BM;
    const int lane = t & 63;
    const int w = t >> 6;

    // ---- stage indices (coalesced: rows g0..g0+31 contiguous) ----
    for (int i = t; i < BM * 11; i += 256) idx_lds[i] = tuples[g0 * 11 + i];
    if (t < BM) tgt_lds[t] = triplets[(g0 + t) * 3 + 2];
    __syncthreads();

    // ---- gather phase: 4 rows at a time, 64 lanes/row, float4/lane ----
    // swizzled LDS layout: phys_byte(L) = L ^ (((L>>10)&7)<<4), L = r*1024 + col*2
    const int rsub = t >> 6;
    for (int step = 0; step < BM / 4; ++step) {
        const int r = step * 4 + rsub;
        float4 acc4 = make_float4(0.f, 0.f, 0.f, 0.f);
        #pragma unroll
        for (int i = 0; i < 10; ++i) {
            int node = idx_lds[r * 11 + 1 + i];
            node = min(max(node, 0), NNODES - 1);  // defensive clamp
            const float4 v = *(const float4*)(gnn_h + node * INF + lane * 4);
            acc4.x += v.x; acc4.y += v.y; acc4.z += v.z; acc4.w += v.w;
        }
        {   // averaged part: cols lane*4 .. lane*4+3
            unsigned long long pk = (unsigned long long)f2bf(acc4.x * 0.1f)
                | ((unsigned long long)f2bf(acc4.y * 0.1f) << 16)
                | ((unsigned long long)f2bf(acc4.z * 0.1f) << 32)
                | ((unsigned long long)f2bf(acc4.w * 0.1f) << 48);
            int byte = (r * 1024 + lane * 8) ^ ((r & 7) << 4);
            *(unsigned long long*)((char*)x_lds + byte) = pk;
        }
        {   // target part: cols 256 + lane*4 ..
            int tgt = tgt_lds[r];
            tgt = min(max(tgt, 0), NNODES - 1);    // defensive clamp
            const float4 v = *(const float4*)(gnn_h + tgt * INF + lane * 4);
            unsigned long long pk = (unsigned long long)f2bf(v.x)
                | ((unsigned long long)f2bf(v.y) << 16)
                | ((unsigned long long)f2bf(v.z) << 32)
                | ((unsigned long long)f2bf(v.w) << 48);
            int byte = (r * 1024 + 512 + lane * 8) ^ ((r & 7) << 4);
            *(unsigned long long*)((char*)x_lds + byte) = pk;
        }
    }
    __syncthreads();

    // ---- MFMA phase: wave w owns h-cols [w*128, w*128+128) ----
    const int wcol0 = w * 128;
    const int arow = lane & 15;   // A row within 16-tile / B col within 16-tile
    const int kgrp = lane >> 4;   // K-chunk selector (8 elems each)

    // preload b1/W2 for this lane's 8 col-tiles
    float b1r[8], w2r[8];
    #pragma unroll
    for (int ct = 0; ct < 8; ++ct) {
        b1r[ct] = b1[wcol0 + ct * 16 + arow];
        w2r[ct] = W2[wcol0 + ct * 16 + arow];
    }

    f32x4 acc[2][8];
    #pragma unroll
    for (int rt = 0; rt < 2; ++rt)
        #pragma unroll
        for (int ct = 0; ct < 8; ++ct)
            acc[rt][ct] = (f32x4){0.f, 0.f, 0.f, 0.f};

    // LOGICAL offsets incremented; XOR applied at use (bit-6 of the swizzle
    // does NOT commute with +=64, so never increment the XORed address).
    const int row0 = arow, row1 = 16 + arow;
    const int x0 = (row0 & 7) << 4;
    const int x1 = (row1 & 7) << 4;
    int loff0 = row0 * 1024 + kgrp * 16;
    int loff1 = row1 * 1024 + kgrp * 16;

    const unsigned short* wbase = g_W1b + (wcol0 + arow) * KDIM + kgrp * 8;

    for (int kk = 0; kk < KDIM; kk += 32) {
        const short8 a0 = *(const short8*)((const char*)x_lds + (loff0 ^ x0));
        const short8 a1 = *(const short8*)((const char*)x_lds + (loff1 ^ x1));
        loff0 += 64; loff1 += 64;
        #pragma unroll
        for (int ct = 0; ct < 8; ++ct) {
            const short8 bf = *(const short8*)(wbase + ct * 16 * KDIM + kk);
            acc[0][ct] = __builtin_amdgcn_mfma_f32_16x16x32_bf16(a0, bf, acc[0][ct], 0, 0, 0);
            acc[1][ct] = __builtin_amdgcn_mfma_f32_16x16x32_bf16(a1, bf, acc[1][ct], 0, 0, 0);
        }
    }

    // ---- epilogue: relu + dot(W2) + cross-lane/wave reduce + sigmoid ----
    // D mapping: col = wcol0 + ct*16 + (lane&15), row = rt*16 + (lane>>4)*4 + reg
    #pragma unroll
    for (int rt = 0; rt < 2; ++rt) {
        #pragma unroll
        for (int reg = 0; reg < 4; ++reg) {
            float s = 0.f;
            #pragma unroll
            for (int ct = 0; ct < 8; ++ct) {
                float h = acc[rt][ct][reg] + b1r[ct];
                h = fmaxf(h, 0.f);
                s += h * w2r[ct];
            }
            s += __shfl_xor(s, 1, 64);
            s += __shfl_xor(s, 2, 64);
            s += __shfl_xor(s, 4, 64);
            s += __shfl_xor(s, 8, 64);
            if ((lane & 15) == 0)
                red[w][rt * 16 + kgrp * 4 + reg] = s;
        }
    }
    __syncthreads();

    if (t < BM) {
        float s = red[0][t] + red[1][t] + red[2][t] + red[3][t] + b2[0];
        out[g0 + t] = 1.f / (1.f + expf(-s));
    }
}

extern "C" void kernel_launch(void* const* d_in, const int* in_sizes, int n_in,
                              void* d_out, int out_size, void* d_ws, size_t ws_size,
                              hipStream_t stream) {
    const float* gnn_h    = (const float*)d_in[0];
    const int*   tuples   = (const int*)d_in[1];
    const int*   triplets = (const int*)d_in[2];
    const float* W1       = (const float*)d_in[3];
    const float* b1       = (const float*)d_in[4];
    const float* W2       = (const float*)d_in[5];
    const float* b2       = (const float*)d_in[6];
    float* out = (float*)d_out;

    convert_w1_kernel<<<dim3(256), dim3(256), 0, stream>>>(W1);
    fused_kernel<<<dim3(NROWS / BM), dim3(256), 0, stream>>>(
        gnn_h, tuples, triplets, b1, W2, b2, out);
}

// Round 5
// 348.205 us; speedup vs baseline: 1.7991x; 1.7991x over previous
//
#include <hip/hip_runtime.h>
#include <hip/hip_bf16.h>

// TupleAveragePredictor: out = sigmoid( relu( [mean(gnn_h[tuples[:,1:]]), gnn_h[triplets[:,2]]] @ W1^T + b1 ) @ W2^T + b2 )
// R5 = R4 with the compile fix (store cast was const-qualified).
// R4: latency attack — (1) gnn_h pre-converted to bf16 (halves gather bytes,
// target half becomes a raw copy), (2) W1 pre-packed into MFMA B-fragment
// order (1 KB contiguous wave-loads instead of 16x64B segments),
// (3) BM=64 / 8 waves / acc[4][4] (halves W1 re-streaming, better MFMA:load).

#define NROWS 200000
#define NNODES 100000
#define INF 256
#define KDIM 512
#define HF 512
#define BM 64

typedef __attribute__((ext_vector_type(8))) short short8;
typedef __attribute__((ext_vector_type(4))) float f32x4;

__device__ __align__(16) unsigned short g_hb[NNODES * INF];   // 51.2 MB bf16 node table
__device__ __align__(16) unsigned short g_W1p[HF * KDIM];     // 512 KB fragment-packed W1

__device__ __forceinline__ unsigned short f2bf(float f) {
    unsigned int u = __float_as_uint(f);
    return (unsigned short)((u + 0x7fffu + ((u >> 16) & 1u)) >> 16);
}
__device__ __forceinline__ float bf2f(unsigned short s) {
    return __uint_as_float(((unsigned int)s) << 16);
}
__device__ __forceinline__ unsigned long long pk4(float a, float b, float c, float d) {
    return (unsigned long long)f2bf(a) | ((unsigned long long)f2bf(b) << 16)
         | ((unsigned long long)f2bf(c) << 32) | ((unsigned long long)f2bf(d) << 48);
}

// gnn_h fp32 -> bf16, 8 elems/thread. 25.6M elems / 8 = 3.2M thr = 12500 blocks.
__global__ void convert_h_kernel(const float* __restrict__ gnn_h) {
    int i = (blockIdx.x * 256 + threadIdx.x) * 8;
    float4 a = *(const float4*)(gnn_h + i);
    float4 b = *(const float4*)(gnn_h + i + 4);
    ulonglong2 v;
    v.x = pk4(a.x, a.y, a.z, a.w);
    v.y = pk4(b.x, b.y, b.z, b.w);
    *(ulonglong2*)(g_hb + i) = v;
}

// W1 -> bf16 packed in B-fragment order:
// packed[(c*16+ki)*512 + lane*8 + j] = W1[col=c*16+(lane&15)][k=ki*32+(lane>>4)*8+j]
// so a wave-load of 64 lanes x 16B at chunk (c,ki) is 1 KB contiguous.
__global__ void pack_w1_kernel(const float* __restrict__ W1) {
    int p = (blockIdx.x * 256 + threadIdx.x) * 4;  // 262144/4 = 65536 thr
    int chunk  = p >> 9;          // c*16 + ki
    int within = p & 511;
    int lane = within >> 3;
    int j0   = within & 7;        // 0 or 4
    int c  = chunk >> 4, ki = chunk & 15;
    int col = c * 16 + (lane & 15);
    int k   = ki * 32 + (lane >> 4) * 8 + j0;
    float4 v = *(const float4*)(W1 + col * KDIM + k);
    *(unsigned long long*)(g_W1p + p) = pk4(v.x, v.y, v.z, v.w);
}

__global__ __launch_bounds__(512, 4)
void fused_kernel(const int* __restrict__ tuples,
                  const int* __restrict__ triplets,
                  const float* __restrict__ b1,
                  const float* __restrict__ W2,
                  const float* __restrict__ b2,
                  float* __restrict__ out) {
    __shared__ __align__(16) unsigned short x_lds[BM * KDIM];  // 64 KB, swizzled
    __shared__ int idx_lds[BM * 11];
    __shared__ int tgt_lds[BM];
    __shared__ float red[8][BM];

    const int t = threadIdx.x;
    const int g0 = blockIdx.x * BM;
    const int lane = t & 63;
    const int wc = t >> 6;          // wave 0..7

    // ---- stage indices ----
    for (int i = t; i < BM * 11; i += 512) idx_lds[i] = tuples[g0 * 11 + i];
    if (t < BM) tgt_lds[t] = triplets[(g0 + t) * 3 + 2];
    __syncthreads();

    // ---- gather: 16 rows/step (2 rows per wave, 32 lanes each), 4 steps ----
    // swizzled LDS: phys = L ^ ((row&7)<<4), L = row*1024 + half*512 + l32*16
    const int rgrp = t >> 5;        // 0..15
    const int l32 = t & 31;
    for (int step = 0; step < BM / 16; ++step) {
        const int r = step * 16 + rgrp;
        short8 u[10];
        #pragma unroll
        for (int i = 0; i < 10; ++i) {
            int node = idx_lds[r * 11 + 1 + i];
            node = min(max(node, 0), NNODES - 1);
            u[i] = *(const short8*)(g_hb + node * INF + l32 * 8);
        }
        int tg = tgt_lds[r];
        tg = min(max(tg, 0), NNODES - 1);
        const short8 ut = *(const short8*)(g_hb + tg * INF + l32 * 8);

        float acc[8] = {0.f, 0.f, 0.f, 0.f, 0.f, 0.f, 0.f, 0.f};
        #pragma unroll
        for (int i = 0; i < 10; ++i)
            #pragma unroll
            for (int j = 0; j < 8; ++j)
                acc[j] += bf2f((unsigned short)u[i][j]);

        ulonglong2 avg;
        avg.x = pk4(acc[0] * 0.1f, acc[1] * 0.1f, acc[2] * 0.1f, acc[3] * 0.1f);
        avg.y = pk4(acc[4] * 0.1f, acc[5] * 0.1f, acc[6] * 0.1f, acc[7] * 0.1f);
        const int x = (r & 7) << 4;
        *(ulonglong2*)((char*)x_lds + ((r * 1024 + l32 * 16) ^ x)) = avg;
        *(short8*)((char*)x_lds + ((r * 1024 + 512 + l32 * 16) ^ x)) = ut;
    }
    __syncthreads();

    // ---- MFMA: wave wc owns h-cols [wc*64, wc*64+64), acc[4 row-tiles][4 col-tiles] ----
    const int arow = lane & 15;
    const int kgrp = lane >> 4;

    float b1r[4], w2r[4];
    #pragma unroll
    for (int ct = 0; ct < 4; ++ct) {
        b1r[ct] = b1[wc * 64 + ct * 16 + arow];
        w2r[ct] = W2[wc * 64 + ct * 16 + arow];
    }

    f32x4 acc[4][4];
    #pragma unroll
    for (int rt = 0; rt < 4; ++rt)
        #pragma unroll
        for (int ct = 0; ct < 4; ++ct)
            acc[rt][ct] = (f32x4){0.f, 0.f, 0.f, 0.f};

    const int xsw = (arow & 7) << 4;   // row&7 == arow&7 (rt*16 doesn't touch low 3 bits)
    for (int ki = 0; ki < 16; ++ki) {
        short8 a[4];
        #pragma unroll
        for (int rt = 0; rt < 4; ++rt) {
            const int loff = (rt * 16 + arow) * 1024 + ki * 64 + kgrp * 16;
            a[rt] = *(const short8*)((const char*)x_lds + (loff ^ xsw));
        }
        #pragma unroll
        for (int ct = 0; ct < 4; ++ct) {
            const short8 b = *(const short8*)(g_W1p + ((wc * 4 + ct) * 16 + ki) * 512 + lane * 8);
            #pragma unroll
            for (int rt = 0; rt < 4; ++rt)
                acc[rt][ct] = __builtin_amdgcn_mfma_f32_16x16x32_bf16(a[rt], b, acc[rt][ct], 0, 0, 0);
        }
    }

    // ---- epilogue: relu + dot(W2) + reduce + sigmoid ----
    // D mapping: col = wc*64 + ct*16 + (lane&15), row = rt*16 + kgrp*4 + reg
    #pragma unroll
    for (int rt = 0; rt < 4; ++rt) {
        #pragma unroll
        for (int reg = 0; reg < 4; ++reg) {
            float s = 0.f;
            #pragma unroll
            for (int ct = 0; ct < 4; ++ct) {
                float h = acc[rt][ct][reg] + b1r[ct];
                s += fmaxf(h, 0.f) * w2r[ct];
            }
            s += __shfl_xor(s, 1, 64);
            s += __shfl_xor(s, 2, 64);
            s += __shfl_xor(s, 4, 64);
            s += __shfl_xor(s, 8, 64);
            if ((lane & 15) == 0)
                red[wc][rt * 16 + kgrp * 4 + reg] = s;
        }
    }
    __syncthreads();

    if (t < BM) {
        float s = b2[0];
        #pragma unroll
        for (int i = 0; i < 8; ++i) s += red[i][t];
        out[g0 + t] = 1.f / (1.f + expf(-s));
    }
}

extern "C" void kernel_launch(void* const* d_in, const int* in_sizes, int n_in,
                              void* d_out, int out_size, void* d_ws, size_t ws_size,
                              hipStream_t stream) {
    const float* gnn_h    = (const float*)d_in[0];
    const int*   tuples   = (const int*)d_in[1];
    const int*   triplets = (const int*)d_in[2];
    const float* W1       = (const float*)d_in[3];
    const float* b1       = (const float*)d_in[4];
    const float* W2       = (const float*)d_in[5];
    const float* b2       = (const float*)d_in[6];
    float* out = (float*)d_out;

    convert_h_kernel<<<dim3(NNODES * INF / (256 * 8)), dim3(256), 0, stream>>>(gnn_h);
    pack_w1_kernel<<<dim3(HF * KDIM / (256 * 4)), dim3(256), 0, stream>>>(W1);
    fused_kernel<<<dim3(NROWS / BM), dim3(512), 0, stream>>>(
        tuples, triplets, b1, W2, b2, out);
}

// Round 6
// 257.520 us; speedup vs baseline: 2.4327x; 1.3521x over previous
//
#include <hip/hip_runtime.h>
#include <hip/hip_bf16.h>

// TupleAveragePredictor: out = sigmoid( relu( [mean(gnn_h[tuples[:,1:]]), gnn_h[triplets[:,2]]] @ W1^T + b1 ) @ W2^T + b2 )
// R6: gather bytes are the limiter (random-512B effective BW ~2.3 TB/s).
// Averaged-half gathers now read a 25.6 MB fp8(e4m3) table (HW cvt_pk_f32_fp8),
// halving gather traffic; target half stays bf16 for accuracy. Structure
// otherwise identical to R5 (BM=64, 8 waves, packed W1, swizzled LDS).

#define NROWS 200000
#define NNODES 100000
#define INF 256
#define KDIM 512
#define HF 512
#define BM 64

typedef __attribute__((ext_vector_type(8))) short short8;
typedef __attribute__((ext_vector_type(4))) float f32x4;
typedef __attribute__((ext_vector_type(2))) float f32x2;

__device__ __align__(16) unsigned short g_hb[NNODES * INF];   // 51.2 MB bf16 (target reads)
__device__ __align__(16) unsigned char  g_h8[NNODES * INF];   // 25.6 MB fp8 e4m3 (avg reads)
__device__ __align__(16) unsigned short g_W1p[HF * KDIM];     // 512 KB fragment-packed W1

__device__ __forceinline__ unsigned short f2bf(float f) {
    unsigned int u = __float_as_uint(f);
    return (unsigned short)((u + 0x7fffu + ((u >> 16) & 1u)) >> 16);
}
__device__ __forceinline__ unsigned long long pk4(float a, float b, float c, float d) {
    return (unsigned long long)f2bf(a) | ((unsigned long long)f2bf(b) << 16)
         | ((unsigned long long)f2bf(c) << 32) | ((unsigned long long)f2bf(d) << 48);
}

// gnn_h fp32 -> bf16 table AND fp8 table, 8 elems/thread (12500 blocks x 256).
__global__ void convert_h_kernel(const float* __restrict__ gnn_h) {
    int i = (blockIdx.x * 256 + threadIdx.x) * 8;
    float4 a = *(const float4*)(gnn_h + i);
    float4 b = *(const float4*)(gnn_h + i + 4);
    ulonglong2 v;
    v.x = pk4(a.x, a.y, a.z, a.w);
    v.y = pk4(b.x, b.y, b.z, b.w);
    *(ulonglong2*)(g_hb + i) = v;
    int w0 = __builtin_amdgcn_cvt_pk_fp8_f32(a.x, a.y, 0, 0);
    w0     = __builtin_amdgcn_cvt_pk_fp8_f32(a.z, a.w, w0, 1);
    int w1 = __builtin_amdgcn_cvt_pk_fp8_f32(b.x, b.y, 0, 0);
    w1     = __builtin_amdgcn_cvt_pk_fp8_f32(b.z, b.w, w1, 1);
    *(uint2*)(g_h8 + i) = make_uint2((unsigned)w0, (unsigned)w1);
}

// W1 -> bf16 packed in B-fragment order:
// packed[(c*16+ki)*512 + lane*8 + j] = W1[col=c*16+(lane&15)][k=ki*32+(lane>>4)*8+j]
__global__ void pack_w1_kernel(const float* __restrict__ W1) {
    int p = (blockIdx.x * 256 + threadIdx.x) * 4;  // 262144/4 = 65536 thr
    int chunk  = p >> 9;
    int within = p & 511;
    int lane = within >> 3;
    int j0   = within & 7;
    int c  = chunk >> 4, ki = chunk & 15;
    int col = c * 16 + (lane & 15);
    int k   = ki * 32 + (lane >> 4) * 8 + j0;
    float4 v = *(const float4*)(W1 + col * KDIM + k);
    *(unsigned long long*)(g_W1p + p) = pk4(v.x, v.y, v.z, v.w);
}

__global__ __launch_bounds__(512, 4)
void fused_kernel(const int* __restrict__ tuples,
                  const int* __restrict__ triplets,
                  const float* __restrict__ b1,
                  const float* __restrict__ W2,
                  const float* __restrict__ b2,
                  float* __restrict__ out) {
    __shared__ __align__(16) unsigned short x_lds[BM * KDIM];  // 64 KB, swizzled
    __shared__ int idx_lds[BM * 11];
    __shared__ int tgt_lds[BM];
    __shared__ float red[8][BM];

    const int t = threadIdx.x;
    const int g0 = blockIdx.x * BM;
    const int lane = t & 63;
    const int wc = t >> 6;

    // ---- stage indices ----
    for (int i = t; i < BM * 11; i += 512) idx_lds[i] = tuples[g0 * 11 + i];
    if (t < BM) tgt_lds[t] = triplets[(g0 + t) * 3 + 2];
    __syncthreads();

    // ---- gather: 16 rows/step (32 lanes per row), 4 steps ----
    // avg half from fp8 table (8B/lane), tgt half from bf16 table (16B/lane).
    // swizzled LDS: phys = L ^ ((row&7)<<4), L = row*1024 + half*512 + l32*16
    const int rgrp = t >> 5;
    const int l32 = t & 31;
    for (int step = 0; step < BM / 16; ++step) {
        const int r = step * 16 + rgrp;
        uint2 u[10];
        #pragma unroll
        for (int i = 0; i < 10; ++i) {
            int node = idx_lds[r * 11 + 1 + i];
            node = min(max(node, 0), NNODES - 1);
            u[i] = *(const uint2*)(g_h8 + node * INF + l32 * 8);
        }
        int tg = tgt_lds[r];
        tg = min(max(tg, 0), NNODES - 1);
        const short8 ut = *(const short8*)(g_hb + tg * INF + l32 * 8);

        f32x2 s0 = {0.f, 0.f}, s1 = {0.f, 0.f}, s2 = {0.f, 0.f}, s3 = {0.f, 0.f};
        #pragma unroll
        for (int i = 0; i < 10; ++i) {
            s0 += __builtin_amdgcn_cvt_pk_f32_fp8((int)u[i].x, 0);
            s1 += __builtin_amdgcn_cvt_pk_f32_fp8((int)u[i].x, 1);
            s2 += __builtin_amdgcn_cvt_pk_f32_fp8((int)u[i].y, 0);
            s3 += __builtin_amdgcn_cvt_pk_f32_fp8((int)u[i].y, 1);
        }

        ulonglong2 avg;
        avg.x = pk4(s0.x * 0.1f, s0.y * 0.1f, s1.x * 0.1f, s1.y * 0.1f);
        avg.y = pk4(s2.x * 0.1f, s2.y * 0.1f, s3.x * 0.1f, s3.y * 0.1f);
        const int x = (r & 7) << 4;
        *(ulonglong2*)((char*)x_lds + ((r * 1024 + l32 * 16) ^ x)) = avg;
        *(short8*)((char*)x_lds + ((r * 1024 + 512 + l32 * 16) ^ x)) = ut;
    }
    __syncthreads();

    // ---- MFMA: wave wc owns h-cols [wc*64, wc*64+64), acc[4][4] ----
    const int arow = lane & 15;
    const int kgrp = lane >> 4;

    float b1r[4], w2r[4];
    #pragma unroll
    for (int ct = 0; ct < 4; ++ct) {
        b1r[ct] = b1[wc * 64 + ct * 16 + arow];
        w2r[ct] = W2[wc * 64 + ct * 16 + arow];
    }

    f32x4 acc[4][4];
    #pragma unroll
    for (int rt = 0; rt < 4; ++rt)
        #pragma unroll
        for (int ct = 0; ct < 4; ++ct)
            acc[rt][ct] = (f32x4){0.f, 0.f, 0.f, 0.f};

    const int xsw = (arow & 7) << 4;
    for (int ki = 0; ki < 16; ++ki) {
        short8 a[4];
        #pragma unroll
        for (int rt = 0; rt < 4; ++rt) {
            const int loff = (rt * 16 + arow) * 1024 + ki * 64 + kgrp * 16;
            a[rt] = *(const short8*)((const char*)x_lds + (loff ^ xsw));
        }
        #pragma unroll
        for (int ct = 0; ct < 4; ++ct) {
            const short8 b = *(const short8*)(g_W1p + ((wc * 4 + ct) * 16 + ki) * 512 + lane * 8);
            #pragma unroll
            for (int rt = 0; rt < 4; ++rt)
                acc[rt][ct] = __builtin_amdgcn_mfma_f32_16x16x32_bf16(a[rt], b, acc[rt][ct], 0, 0, 0);
        }
    }

    // ---- epilogue: relu + dot(W2) + reduce + sigmoid ----
    // D mapping: col = wc*64 + ct*16 + (lane&15), row = rt*16 + kgrp*4 + reg
    #pragma unroll
    for (int rt = 0; rt < 4; ++rt) {
        #pragma unroll
        for (int reg = 0; reg < 4; ++reg) {
            float s = 0.f;
            #pragma unroll
            for (int ct = 0; ct < 4; ++ct) {
                float h = acc[rt][ct][reg] + b1r[ct];
                s += fmaxf(h, 0.f) * w2r[ct];
            }
            s += __shfl_xor(s, 1, 64);
            s += __shfl_xor(s, 2, 64);
            s += __shfl_xor(s, 4, 64);
            s += __shfl_xor(s, 8, 64);
            if ((lane & 15) == 0)
                red[wc][rt * 16 + kgrp * 4 + reg] = s;
        }
    }
    __syncthreads();

    if (t < BM) {
        float s = b2[0];
        #pragma unroll
        for (int i = 0; i < 8; ++i) s += red[i][t];
        out[g0 + t] = 1.f / (1.f + expf(-s));
    }
}

extern "C" void kernel_launch(void* const* d_in, const int* in_sizes, int n_in,
                              void* d_out, int out_size, void* d_ws, size_t ws_size,
                              hipStream_t stream) {
    const float* gnn_h    = (const float*)d_in[0];
    const int*   tuples   = (const int*)d_in[1];
    const int*   triplets = (const int*)d_in[2];
    const float* W1       = (const float*)d_in[3];
    const float* b1       = (const float*)d_in[4];
    const float* W2       = (const float*)d_in[5];
    const float* b2       = (const float*)d_in[6];
    float* out = (float*)d_out;

    convert_h_kernel<<<dim3(NNODES * INF / (256 * 8)), dim3(256), 0, stream>>>(gnn_h);
    pack_w1_kernel<<<dim3(HF * KDIM / (256 * 4)), dim3(256), 0, stream>>>(W1);
    fused_kernel<<<dim3(NROWS / BM), dim3(512), 0, stream>>>(
        tuples, triplets, b1, W2, b2, out);
}